// Round 14
// baseline (222.636 us; speedup 1.0000x reference)
//
#include <hip/hip_runtime.h>
#include <math.h>

#define NEG_SLOPE 0.2f
#define BKT_SHIFT 8                 // 256 dst nodes per bucket
#define BKT_RANGE 256
#define EPB 4096                    // edges per block in binning kernels

typedef __attribute__((ext_vector_type(8))) short bf16x8;
typedef __attribute__((ext_vector_type(4))) float f32x4;

__device__ __forceinline__ float elu1(float x)  { return x > 0.f ? x : expm1f(x); }

__device__ __forceinline__ unsigned short f2bf(float f) {
  unsigned u = __float_as_uint(f);
  unsigned r = (u + 0x7FFFu + ((u >> 16) & 1u)) >> 16;
  return (unsigned short)r;
}
__device__ __forceinline__ float bflo(unsigned u) { return __uint_as_float(u << 16); }
__device__ __forceinline__ float bfhi(unsigned u) { return __uint_as_float(u & 0xFFFF0000u); }
// HW packed f32->bf16 (RNE)
__device__ __forceinline__ unsigned cvt_pk_bf16(float lo, float hi) {
  unsigned r;
  asm("v_cvt_pk_bf16_f32 %0, %1, %2" : "=v"(r) : "v"(lo), "v"(hi));
  return r;
}

// ---------------- K1: MFMA GEMM (A direct-to-reg) + fused alpha/fp8 epilogue ----------------
// hx row per node: 32 u32 = 128B ALIGNED.
//   words 0..7  : packed {exp(as),exp(.2as)} per head (src-side)
//   words 8..15 : packed {exp(ad),exp(.2ad)} per head (dst-side)
//   words 16..31: 64 channels fp8 e4m3 (one 64B line)
__global__ __launch_bounds__(256) void k_gemm1_mfma(const float* __restrict__ x,
                                                    const unsigned short* __restrict__ Wt,
                                                    const float* __restrict__ a1s,
                                                    const float* __restrict__ a1d,
                                                    unsigned* __restrict__ hx, int N) {
  __shared__ __align__(16) float Sm[64 * 64];        // 16 KB: Bs in loop, Asf in epilogue
  unsigned short* Bs = (unsigned short*)Sm;
  float* Asf = Sm;
  const int t = threadIdx.x;
  const int w = t >> 6;
  const int l = t & 63;
  const int fr = l & 15;
  const int fq = l >> 4;
  const int rowbase = blockIdx.x * 128;
  f32x4 acc[2][4] = {};

  const int r0g = rowbase + w * 32 + fr;
  const int r1g = r0g + 16;
  const bool v0 = r0g < N, v1 = r1g < N;
  const float* xr0 = x + (size_t)r0g * 512 + fq * 8;
  const float* xr1 = x + (size_t)r1g * 512 + fq * 8;

  for (int k0 = 0; k0 < 512; k0 += 64) {
#pragma unroll
    for (int rep = 0; rep < 2; ++rep) {
      int i = t + rep * 256;
      int c = i >> 3, ch = i & 7;
      uint4 v = *(const uint4*)(Wt + (size_t)c * 512 + k0 + ch * 8);
      *((uint4*)(Bs + c * 64 + (ch ^ (c & 7)) * 8)) = v;
    }
    bf16x8 a[2][2];
#pragma unroll
    for (int m = 0; m < 2; ++m) {
      const float* xr = m ? xr1 : xr0;
      bool vv = m ? v1 : v0;
#pragma unroll
      for (int ks = 0; ks < 2; ++ks) {
        float4 f0 = make_float4(0.f, 0.f, 0.f, 0.f), f1 = f0;
        if (vv) {
          f0 = *(const float4*)(xr + k0 + ks * 32);
          f1 = *(const float4*)(xr + k0 + ks * 32 + 4);
        }
        union { unsigned u[4]; bf16x8 v8; } un;
        un.u[0] = cvt_pk_bf16(f0.x, f0.y);
        un.u[1] = cvt_pk_bf16(f0.z, f0.w);
        un.u[2] = cvt_pk_bf16(f1.x, f1.y);
        un.u[3] = cvt_pk_bf16(f1.z, f1.w);
        a[m][ks] = un.v8;
      }
    }
    __syncthreads();
#pragma unroll
    for (int ks = 0; ks < 2; ++ks) {
      bf16x8 b[4];
#pragma unroll
      for (int n = 0; n < 4; ++n) {
        int c = n * 16 + fr;
        int ch = (ks * 4 + fq) ^ (c & 7);
        b[n] = *((const bf16x8*)(Bs + c * 64 + ch * 8));
      }
#pragma unroll
      for (int m = 0; m < 2; ++m)
#pragma unroll
        for (int n = 0; n < 4; ++n)
          acc[m][n] = __builtin_amdgcn_mfma_f32_16x16x32_bf16(a[m][ks], b[n], acc[m][n], 0, 0, 0);
    }
    __syncthreads();
  }

  // ---- fused epilogue: stage tile half (64x64 f32) in LDS
#pragma unroll
  for (int m = 0; m < 2; ++m) {
    if (m) __syncthreads();
#pragma unroll
    for (int reg = 0; reg < 4; ++reg) {
      int lrow = w * 16 + fq * 4 + reg;
#pragma unroll
      for (int n = 0; n < 4; ++n)
        Asf[lrow * 64 + n * 16 + fr] = acc[m][n][reg];
    }
    __syncthreads();
    // fp8 pack -> hx words 16..31
#pragma unroll
    for (int p = 0; p < 4; ++p) {
      int flat = p * 256 + t;
      int lrow = flat >> 4, j = flat & 15;
      int g = rowbase + ((lrow >> 4) << 5) + m * 16 + (lrow & 15);
      float4 f = *(float4*)(Asf + lrow * 64 + j * 4);
      unsigned u = __builtin_amdgcn_cvt_pk_fp8_f32(f.x, f.y, 0u, 0);
      u = __builtin_amdgcn_cvt_pk_fp8_f32(f.z, f.w, u, 1);
      if (g < N) hx[(size_t)g * 32 + 16 + j] = u;
    }
    // alpha tables -> hx words 0..7 (src) and 8..15 (dst)
#pragma unroll
    for (int p = 0; p < 2; ++p) {
      int flat = p * 256 + t;
      int lrow = flat >> 3, hh = flat & 7;
      int g = rowbase + ((lrow >> 4) << 5) + m * 16 + (lrow & 15);
      float4 f0 = *(float4*)(Asf + lrow * 64 + hh * 8);
      float4 f1 = *(float4*)(Asf + lrow * 64 + hh * 8 + 4);
      const float* sa = a1s + hh * 8;
      const float* da = a1d + hh * 8;
      float ss = f0.x*sa[0]+f0.y*sa[1]+f0.z*sa[2]+f0.w*sa[3]
               + f1.x*sa[4]+f1.y*sa[5]+f1.z*sa[6]+f1.w*sa[7];
      float dd = f0.x*da[0]+f0.y*da[1]+f0.z*da[2]+f0.w*da[3]
               + f1.x*da[4]+f1.y*da[5]+f1.z*da[6]+f1.w*da[7];
      if (g < N) {
        hx[(size_t)g * 32 + hh]     = cvt_pk_bf16(expf(ss), expf(NEG_SLOPE * ss));
        hx[(size_t)g * 32 + 8 + hh] = cvt_pk_bf16(expf(dd), expf(NEG_SLOPE * dd));
      }
    }
  }
}

// ---------------- CSR build ----------------
__global__ __launch_bounds__(256) void k_bhist_cvtW(const int* __restrict__ dst,
                                                    int* __restrict__ bucketCount,
                                                    const float* __restrict__ W,
                                                    unsigned short* __restrict__ Wt,
                                                    int E, int B, int EB) {
  int blk = blockIdx.x;
  int t = threadIdx.x;
  if (blk >= EB) {
    int i = (blk - EB) * 256 + t;   // i = k*64 + c
    if (i < 512 * 64) {
      int k = i >> 6, c = i & 63;
      Wt[(size_t)c * 512 + k] = f2bf(W[i]);
    }
    return;
  }
  __shared__ int h[512];
  for (int i = t; i < B; i += 256) h[i] = 0;
  __syncthreads();
  int e0 = blk * EPB;
#pragma unroll
  for (int i = 0; i < EPB / 256; ++i) {
    int e = e0 + i * 256 + t;
    if (e < E) atomicAdd(&h[dst[e] >> BKT_SHIFT], 1);
  }
  __syncthreads();
  for (int i = t; i < B; i += 256)
    if (h[i]) atomicAdd(bucketCount + i, h[i]);
}

__global__ __launch_bounds__(256) void k_bin(const int* __restrict__ src,
                                             const int* __restrict__ dst,
                                             const int* __restrict__ bucketCount,
                                             int* __restrict__ gCursorRel,
                                             unsigned* __restrict__ binned,
                                             int E, int B) {
  __shared__ int sc[512];
  __shared__ int hist[512];
  __shared__ int base[512];
  int t = threadIdx.x;
  sc[t]       = (t < B) ? bucketCount[t] : 0;
  sc[t + 256] = (t + 256 < B) ? bucketCount[t + 256] : 0;
  for (int i = t; i < 512; i += 256) hist[i] = 0;
  __syncthreads();
  for (int o = 1; o < 512; o <<= 1) {
    int a0 = (t >= o) ? sc[t - o] : 0;
    int a1 = (t + 256 >= o) ? sc[t + 256 - o] : 0;
    __syncthreads();
    sc[t] += a0;
    sc[t + 256] += a1;
    __syncthreads();
  }
  int e0 = blockIdx.x * EPB;
#pragma unroll
  for (int i = 0; i < EPB / 256; ++i) {
    int e = e0 + i * 256 + t;
    if (e < E) atomicAdd(&hist[dst[e] >> BKT_SHIFT], 1);
  }
  __syncthreads();
  for (int i = t; i < B; i += 256) {
    int c = hist[i];
    int excl = sc[i] - bucketCount[i];
    base[i] = c ? (excl + atomicAdd(gCursorRel + i, c)) : 0;
    hist[i] = 0;
  }
  __syncthreads();
#pragma unroll
  for (int i = 0; i < EPB / 256; ++i) {
    int e = e0 + i * 256 + t;
    if (e < E) {
      int d = dst[e];
      int b = d >> BKT_SHIFT;
      int r = atomicAdd(&hist[b], 1);
      binned[base[b] + r] = ((unsigned)(d & (BKT_RANGE - 1)) << 24) | (unsigned)src[e];
    }
  }
}

__global__ __launch_bounds__(256) void k_build(const int* __restrict__ bucketCount,
                                               const unsigned* __restrict__ binned,
                                               int* __restrict__ rowptr,
                                               int* __restrict__ deg,
                                               int* __restrict__ srt, int N, int B) {
  __shared__ int sc[512];
  __shared__ int ldeg[BKT_RANGE];
  __shared__ int sm[BKT_RANGE];
  __shared__ int lcur[BKT_RANGE];
  int t = threadIdx.x;
  int b = blockIdx.x;
  sc[t]       = (t < B) ? bucketCount[t] : 0;
  sc[t + 256] = (t + 256 < B) ? bucketCount[t + 256] : 0;
  ldeg[t] = 0;
  __syncthreads();
  for (int o = 1; o < 512; o <<= 1) {
    int a0 = (t >= o) ? sc[t - o] : 0;
    int a1 = (t + 256 >= o) ? sc[t + 256 - o] : 0;
    __syncthreads();
    sc[t] += a0;
    sc[t + 256] += a1;
    __syncthreads();
  }
  int eend = sc[b];
  int estart = eend - bucketCount[b];
  int nbase = b * BKT_RANGE;
  for (int e = estart + t; e < eend; e += 256)
    atomicAdd(&ldeg[binned[e] >> 24], 1);
  __syncthreads();
  int v = ldeg[t];
  sm[t] = v;
  __syncthreads();
  int acc = v;
#pragma unroll
  for (int o = 1; o < 256; o <<= 1) {
    int u = (t >= o) ? sm[t - o] : 0;
    __syncthreads();
    acc += u;
    sm[t] = acc;
    __syncthreads();
  }
  int excl = estart + acc - v;
  int node = nbase + t;
  if (node < N) {
    rowptr[node] = excl;
    deg[node] = v;
  }
  lcur[t] = excl;
  __syncthreads();
  for (int e = estart + t; e < eend; e += 256) {
    unsigned p = binned[e];
    int pos = atomicAdd(&lcur[p >> 24], 1);
    srt[pos] = (int)(p & 0xFFFFFFu);
  }
}

// ---------------- K agg1f: gather-reduce L1, 8 slots x 8 ch/lane + fused L2 node work ----------------
// lane = slot*8 + c8; slot in [0,8) = edge subset; c8 = head index; lane covers
// channels 8*c8..8*c8+7 (one full head). 8 edges in flight per wave.
__global__ __launch_bounds__(256) void k_agg1f(const int* __restrict__ rowptr,
                                               const int* __restrict__ deg,
                                               const int* __restrict__ srt,
                                               const unsigned* __restrict__ hx,
                                               const float* __restrict__ b1,
                                               const float* __restrict__ W2,
                                               const float* __restrict__ a2s,
                                               const float* __restrict__ a2d,
                                               unsigned* __restrict__ h2x, int N) {
  __shared__ float vsm[4][64];
  const int t = threadIdx.x;
  const int w = t >> 6;
  const int lane = t & 63;
  const int wid = blockIdx.x * 4 + w;
  const int slot = lane >> 3;      // 0..7
  const int c8 = lane & 7;         // head
  // matvec lane mapping (16 lanes x 16-deep each)
  const int slot4 = lane >> 4;
  const int c4 = lane & 15;
  float a2sr = a2s[c4];
  float a2dr = a2d[c4];
  float wreg[16];
#pragma unroll
  for (int m = 0; m < 16; ++m) wreg[m] = W2[(slot4 * 16 + m) * 16 + c4];
  if (wid >= N) return;
  const int d = wid;

  unsigned ddu = hx[(size_t)d * 32 + 8 + c8];
  float ddx = bflo(ddu), ddy = bfhi(ddu);
  // self loop (slot 0 only)
  unsigned es0 = hx[(size_t)d * 32 + c8];
  uint2 sv = *(const uint2*)(hx + (size_t)d * 32 + 16 + c8 * 2);
  float ex0 = fmaxf(bflo(es0) * ddx, bfhi(es0) * ddy);
  ex0 = (slot == 0) ? ex0 : 0.f;
  float a0 = ex0 * __builtin_amdgcn_cvt_f32_fp8(sv.x, 0);
  float a1 = ex0 * __builtin_amdgcn_cvt_f32_fp8(sv.x, 1);
  float a2 = ex0 * __builtin_amdgcn_cvt_f32_fp8(sv.x, 2);
  float a3 = ex0 * __builtin_amdgcn_cvt_f32_fp8(sv.x, 3);
  float a4 = ex0 * __builtin_amdgcn_cvt_f32_fp8(sv.y, 0);
  float a5 = ex0 * __builtin_amdgcn_cvt_f32_fp8(sv.y, 1);
  float a6 = ex0 * __builtin_amdgcn_cvt_f32_fp8(sv.y, 2);
  float a7 = ex0 * __builtin_amdgcn_cvt_f32_fp8(sv.y, 3);
  float den = ex0;

  int start = rowptr[d];
  int len = deg[d];
  for (int kb = 0; kb < len; kb += 64) {
    int li = kb + lane;
    int sreg = (li < len) ? srt[start + li] : 0;
    int nit = min(8, (len - kb + 7) >> 3);
#pragma unroll 4
    for (int it = 0; it < nit; ++it) {
      int idx = kb + it * 8 + slot;
      int s = __shfl(sreg, it * 8 + slot);
      bool valid = idx < len;
      unsigned es = hx[(size_t)s * 32 + c8];
      uint2 hv = *(const uint2*)(hx + (size_t)s * 32 + 16 + c8 * 2);
      float ex = fmaxf(bflo(es) * ddx, bfhi(es) * ddy);
      ex = valid ? ex : 0.f;
      a0 = fmaf(ex, __builtin_amdgcn_cvt_f32_fp8(hv.x, 0), a0);
      a1 = fmaf(ex, __builtin_amdgcn_cvt_f32_fp8(hv.x, 1), a1);
      a2 = fmaf(ex, __builtin_amdgcn_cvt_f32_fp8(hv.x, 2), a2);
      a3 = fmaf(ex, __builtin_amdgcn_cvt_f32_fp8(hv.x, 3), a3);
      a4 = fmaf(ex, __builtin_amdgcn_cvt_f32_fp8(hv.y, 0), a4);
      a5 = fmaf(ex, __builtin_amdgcn_cvt_f32_fp8(hv.y, 1), a5);
      a6 = fmaf(ex, __builtin_amdgcn_cvt_f32_fp8(hv.y, 2), a6);
      a7 = fmaf(ex, __builtin_amdgcn_cvt_f32_fp8(hv.y, 3), a7);
      den += ex;
    }
  }
  // reduce across slots (lane bits 3,4,5)
#pragma unroll
  for (int o = 8; o < 64; o <<= 1) {
    a0 += __shfl_xor(a0, o);
    a1 += __shfl_xor(a1, o);
    a2 += __shfl_xor(a2, o);
    a3 += __shfl_xor(a3, o);
    a4 += __shfl_xor(a4, o);
    a5 += __shfl_xor(a5, o);
    a6 += __shfl_xor(a6, o);
    a7 += __shfl_xor(a7, o);
    den += __shfl_xor(den, o);
  }
  float rden = 1.f / (den + 1e-16f);
  // ---- fused layer-2 node work ----
  if (slot == 0) {
    float4 bA = *(const float4*)(b1 + c8 * 8);
    float4 bB = *(const float4*)(b1 + c8 * 8 + 4);
    float4 vA, vB;
    vA.x = elu1(a0 * rden + bA.x);
    vA.y = elu1(a1 * rden + bA.y);
    vA.z = elu1(a2 * rden + bA.z);
    vA.w = elu1(a3 * rden + bA.w);
    vB.x = elu1(a4 * rden + bB.x);
    vB.y = elu1(a5 * rden + bB.y);
    vB.z = elu1(a6 * rden + bB.z);
    vB.w = elu1(a7 * rden + bB.w);
    *(float4*)&vsm[w][c8 * 8]     = vA;
    *(float4*)&vsm[w][c8 * 8 + 4] = vB;
  }
  float partial = 0.f;
#pragma unroll
  for (int m = 0; m < 16; ++m) partial = fmaf(vsm[w][slot4 * 16 + m], wreg[m], partial);
  float qs = partial * a2sr;
  float qd = partial * a2dr;
#pragma unroll
  for (int o = 1; o < 64; o <<= 1) {
    qs += __shfl_xor(qs, o);
    qd += __shfl_xor(qd, o);
  }
  float p2 = partial + __shfl_down(partial, 32);
  float hcv = p2 + __shfl_down(p2, 16);
  if (lane < 16)
    ((unsigned short*)h2x)[(size_t)d * 32 + 8 + c4] = f2bf(hcv);
  if (lane == 0) {
    h2x[(size_t)d * 16] = cvt_pk_bf16(expf(qs), expf(NEG_SLOPE * qs));
    *(float2*)(h2x + (size_t)d * 16 + 2) = make_float2(expf(qd), expf(NEG_SLOPE * qd));
  }
}

// ---------------- K agg2: gather-reduce layer 2 (64B h2x rows) + b2 + log_softmax ----------------
__global__ __launch_bounds__(256) void k_agg2(const int* __restrict__ rowptr,
                                              const int* __restrict__ deg,
                                              const int* __restrict__ srt,
                                              const unsigned* __restrict__ h2x,
                                              const float* __restrict__ b2,
                                              float* __restrict__ out, int N) {
  const int t = threadIdx.x;
  const int lane = t & 63;
  const int wid = (blockIdx.x * 256 + t) >> 6;
  const int slot = lane >> 2;
  const int cg = lane & 3;
  float4 b2v = *(const float4*)(b2 + cg * 4);
  if (wid >= N) return;
  const int d = wid;
  float2 ddp = *(const float2*)(h2x + (size_t)d * 16 + 2);
  unsigned ps0 = h2x[(size_t)d * 16];
  uint2 sv = *(const uint2*)(h2x + (size_t)d * 16 + 4 + cg * 2);
  float ex0 = fmaxf(bflo(ps0) * ddp.x, bfhi(ps0) * ddp.y);
  ex0 = (slot == 0) ? ex0 : 0.f;
  float a0 = ex0 * bflo(sv.x), a1 = ex0 * bfhi(sv.x);
  float a2 = ex0 * bflo(sv.y), a3 = ex0 * bfhi(sv.y);
  float den = ex0;

  int start = rowptr[d];
  int len = deg[d];
  for (int kb = 0; kb < len; kb += 64) {
    int li = kb + lane;
    int sreg = (li < len) ? srt[start + li] : 0;
    int nit = min(4, (len - kb + 15) >> 4);
#pragma unroll 4
    for (int it = 0; it < nit; ++it) {
      int idx = kb + it * 16 + slot;
      int s = __shfl(sreg, it * 16 + slot);
      bool valid = idx < len;
      unsigned ps = h2x[(size_t)s * 16];
      uint2 hv = *(const uint2*)(h2x + (size_t)s * 16 + 4 + cg * 2);
      float ex = fmaxf(bflo(ps) * ddp.x, bfhi(ps) * ddp.y);
      ex = valid ? ex : 0.f;
      a0 = fmaf(ex, bflo(hv.x), a0);
      a1 = fmaf(ex, bfhi(hv.x), a1);
      a2 = fmaf(ex, bflo(hv.y), a2);
      a3 = fmaf(ex, bfhi(hv.y), a3);
      den += ex;
    }
  }
#pragma unroll
  for (int o = 4; o < 64; o <<= 1) {
    a0 += __shfl_xor(a0, o);
    a1 += __shfl_xor(a1, o);
    a2 += __shfl_xor(a2, o);
    a3 += __shfl_xor(a3, o);
    den += __shfl_xor(den, o);
  }
  float rden = 1.f / (den + 1e-16f);
  float v0 = a0 * rden + b2v.x;
  float v1 = a1 * rden + b2v.y;
  float v2 = a2 * rden + b2v.z;
  float v3 = a3 * rden + b2v.w;
  float m = fmaxf(fmaxf(v0, v1), fmaxf(v2, v3));
  m = fmaxf(m, __shfl_xor(m, 1));
  m = fmaxf(m, __shfl_xor(m, 2));
  float s = expf(v0 - m) + expf(v1 - m) + expf(v2 - m) + expf(v3 - m);
  s += __shfl_xor(s, 1);
  s += __shfl_xor(s, 2);
  float lse = m + logf(s);
  if (lane < 4) {
    float4 o4 = make_float4(v0 - lse, v1 - lse, v2 - lse, v3 - lse);
    *(float4*)(out + (size_t)d * 16 + cg * 4) = o4;
  }
}

extern "C" void kernel_launch(void* const* d_in, const int* in_sizes, int n_in,
                              void* d_out, int out_size, void* d_ws, size_t ws_size,
                              hipStream_t stream) {
  const float* x    = (const float*)d_in[0];
  const int*   ei   = (const int*)d_in[1];
  const float* W1   = (const float*)d_in[2];
  const float* a1s  = (const float*)d_in[3];
  const float* a1d  = (const float*)d_in[4];
  const float* b1   = (const float*)d_in[5];
  const float* W2   = (const float*)d_in[6];
  const float* a2s  = (const float*)d_in[7];
  const float* a2d  = (const float*)d_in[8];
  const float* b2   = (const float*)d_in[9];
  float* out = (float*)d_out;

  const int N = in_sizes[0] / 512;
  const int E = in_sizes[1] / 2;
  const int* src = ei;
  const int* dst = ei + E;
  const int B = (N + BKT_RANGE - 1) >> BKT_SHIFT;
  const int EB = (E + EPB - 1) / EPB;

  float* w = (float*)d_ws;
  unsigned* hx  = (unsigned*)w;             w += (size_t)N * 32;   // 128B rows
  unsigned* h2x = (unsigned*)w;             w += (size_t)N * 16;   // 64B rows
  unsigned short* Wt = (unsigned short*)w;  w += 512 * 64 / 2;
  int* iw = (int*)w;
  int* deg         = iw;  iw += N;
  int* rowptr      = iw;  iw += N;
  int* bucketCount = iw;  iw += 512;
  int* gCursorRel  = iw;  iw += 512;
  int* srt         = iw;  iw += E;
  unsigned* binned = (unsigned*)iw;  iw += E;

  // zero bucketCount + gCursorRel (contiguous 1024 ints)
  (void)hipMemsetAsync(bucketCount, 0, 1024 * sizeof(int), stream);

  // CSR build (+ fused Wt conversion blocks)
  k_bhist_cvtW<<<EB + 128, 256, 0, stream>>>(dst, bucketCount, W1, Wt, E, B, EB);
  k_bin<<<EB, 256, 0, stream>>>(src, dst, bucketCount, gCursorRel, binned, E, B);
  k_build<<<B, 256, 0, stream>>>(bucketCount, binned, rowptr, deg, srt, N, B);

  // Layer 1: GEMM with fused alpha/fp8 epilogue, then gather (+fused L2 node work)
  k_gemm1_mfma<<<(N + 127) / 128, 256, 0, stream>>>(x, Wt, a1s, a1d, hx, N);
  k_agg1f<<<(N + 3) / 4, 256, 0, stream>>>(rowptr, deg, srt, hx,
                                           b1, W2, a2s, a2d, h2x, N);

  // Layer 2
  k_agg2<<<(N + 3) / 4, 256, 0, stream>>>(rowptr, deg, srt, h2x, b2, out, N);
}

// Round 15
// 210.557 us; speedup vs baseline: 1.0574x; 1.0574x over previous
//
#include <hip/hip_runtime.h>
#include <math.h>

#define NEG_SLOPE 0.2f
#define BKT_SHIFT 8                 // 256 dst nodes per bucket
#define BKT_RANGE 256
#define EPB 4096                    // edges per block in binning kernels

typedef __attribute__((ext_vector_type(8))) short bf16x8;
typedef __attribute__((ext_vector_type(4))) float f32x4;

__device__ __forceinline__ float elu1(float x)  { return x > 0.f ? x : expm1f(x); }

__device__ __forceinline__ unsigned short f2bf(float f) {
  unsigned u = __float_as_uint(f);
  unsigned r = (u + 0x7FFFu + ((u >> 16) & 1u)) >> 16;
  return (unsigned short)r;
}
__device__ __forceinline__ float bflo(unsigned u) { return __uint_as_float(u << 16); }
__device__ __forceinline__ float bfhi(unsigned u) { return __uint_as_float(u & 0xFFFF0000u); }
// HW packed f32->bf16 (RNE)
__device__ __forceinline__ unsigned cvt_pk_bf16(float lo, float hi) {
  unsigned r;
  asm("v_cvt_pk_bf16_f32 %0, %1, %2" : "=v"(r) : "v"(lo), "v"(hi));
  return r;
}

// ---------------- K1: MFMA GEMM (A direct-to-reg) + fused alpha/fp8 epilogue ----------------
// hx row per node: 32 u32 = 128B ALIGNED.
//   words 0..7  : packed {exp(as),exp(.2as)} per head (src-side)
//   words 8..15 : packed {exp(ad),exp(.2ad)} per head (dst-side)
//   words 16..31: 64 channels fp8 e4m3 (one 64B line)
__global__ __launch_bounds__(256) void k_gemm1_mfma(const float* __restrict__ x,
                                                    const unsigned short* __restrict__ Wt,
                                                    const float* __restrict__ a1s,
                                                    const float* __restrict__ a1d,
                                                    unsigned* __restrict__ hx, int N) {
  __shared__ __align__(16) float Sm[64 * 64];        // 16 KB: Bs in loop, Asf in epilogue
  unsigned short* Bs = (unsigned short*)Sm;
  float* Asf = Sm;
  const int t = threadIdx.x;
  const int w = t >> 6;
  const int l = t & 63;
  const int fr = l & 15;
  const int fq = l >> 4;
  const int rowbase = blockIdx.x * 128;
  f32x4 acc[2][4] = {};

  const int r0g = rowbase + w * 32 + fr;
  const int r1g = r0g + 16;
  const bool v0 = r0g < N, v1 = r1g < N;
  const float* xr0 = x + (size_t)r0g * 512 + fq * 8;
  const float* xr1 = x + (size_t)r1g * 512 + fq * 8;

  for (int k0 = 0; k0 < 512; k0 += 64) {
#pragma unroll
    for (int rep = 0; rep < 2; ++rep) {
      int i = t + rep * 256;
      int c = i >> 3, ch = i & 7;
      uint4 v = *(const uint4*)(Wt + (size_t)c * 512 + k0 + ch * 8);
      *((uint4*)(Bs + c * 64 + (ch ^ (c & 7)) * 8)) = v;
    }
    bf16x8 a[2][2];
#pragma unroll
    for (int m = 0; m < 2; ++m) {
      const float* xr = m ? xr1 : xr0;
      bool vv = m ? v1 : v0;
#pragma unroll
      for (int ks = 0; ks < 2; ++ks) {
        float4 f0 = make_float4(0.f, 0.f, 0.f, 0.f), f1 = f0;
        if (vv) {
          f0 = *(const float4*)(xr + k0 + ks * 32);
          f1 = *(const float4*)(xr + k0 + ks * 32 + 4);
        }
        union { unsigned u[4]; bf16x8 v8; } un;
        un.u[0] = cvt_pk_bf16(f0.x, f0.y);
        un.u[1] = cvt_pk_bf16(f0.z, f0.w);
        un.u[2] = cvt_pk_bf16(f1.x, f1.y);
        un.u[3] = cvt_pk_bf16(f1.z, f1.w);
        a[m][ks] = un.v8;
      }
    }
    __syncthreads();
#pragma unroll
    for (int ks = 0; ks < 2; ++ks) {
      bf16x8 b[4];
#pragma unroll
      for (int n = 0; n < 4; ++n) {
        int c = n * 16 + fr;
        int ch = (ks * 4 + fq) ^ (c & 7);
        b[n] = *((const bf16x8*)(Bs + c * 64 + ch * 8));
      }
#pragma unroll
      for (int m = 0; m < 2; ++m)
#pragma unroll
        for (int n = 0; n < 4; ++n)
          acc[m][n] = __builtin_amdgcn_mfma_f32_16x16x32_bf16(a[m][ks], b[n], acc[m][n], 0, 0, 0);
    }
    __syncthreads();
  }

  // ---- fused epilogue: stage tile half (64x64 f32) in LDS
#pragma unroll
  for (int m = 0; m < 2; ++m) {
    if (m) __syncthreads();
#pragma unroll
    for (int reg = 0; reg < 4; ++reg) {
      int lrow = w * 16 + fq * 4 + reg;
#pragma unroll
      for (int n = 0; n < 4; ++n)
        Asf[lrow * 64 + n * 16 + fr] = acc[m][n][reg];
    }
    __syncthreads();
    // fp8 pack -> hx words 16..31
#pragma unroll
    for (int p = 0; p < 4; ++p) {
      int flat = p * 256 + t;
      int lrow = flat >> 4, j = flat & 15;
      int g = rowbase + ((lrow >> 4) << 5) + m * 16 + (lrow & 15);
      float4 f = *(float4*)(Asf + lrow * 64 + j * 4);
      unsigned u = __builtin_amdgcn_cvt_pk_fp8_f32(f.x, f.y, 0u, 0);
      u = __builtin_amdgcn_cvt_pk_fp8_f32(f.z, f.w, u, 1);
      if (g < N) hx[(size_t)g * 32 + 16 + j] = u;
    }
    // alpha tables -> hx words 0..7 (src) and 8..15 (dst)
#pragma unroll
    for (int p = 0; p < 2; ++p) {
      int flat = p * 256 + t;
      int lrow = flat >> 3, hh = flat & 7;
      int g = rowbase + ((lrow >> 4) << 5) + m * 16 + (lrow & 15);
      float4 f0 = *(float4*)(Asf + lrow * 64 + hh * 8);
      float4 f1 = *(float4*)(Asf + lrow * 64 + hh * 8 + 4);
      const float* sa = a1s + hh * 8;
      const float* da = a1d + hh * 8;
      float ss = f0.x*sa[0]+f0.y*sa[1]+f0.z*sa[2]+f0.w*sa[3]
               + f1.x*sa[4]+f1.y*sa[5]+f1.z*sa[6]+f1.w*sa[7];
      float dd = f0.x*da[0]+f0.y*da[1]+f0.z*da[2]+f0.w*da[3]
               + f1.x*da[4]+f1.y*da[5]+f1.z*da[6]+f1.w*da[7];
      if (g < N) {
        hx[(size_t)g * 32 + hh]     = cvt_pk_bf16(expf(ss), expf(NEG_SLOPE * ss));
        hx[(size_t)g * 32 + 8 + hh] = cvt_pk_bf16(expf(dd), expf(NEG_SLOPE * dd));
      }
    }
  }
}

// ---------------- CSR build ----------------
__global__ __launch_bounds__(256) void k_bhist_cvtW(const int* __restrict__ dst,
                                                    int* __restrict__ bucketCount,
                                                    const float* __restrict__ W,
                                                    unsigned short* __restrict__ Wt,
                                                    int E, int B, int EB) {
  int blk = blockIdx.x;
  int t = threadIdx.x;
  if (blk >= EB) {
    int i = (blk - EB) * 256 + t;   // i = k*64 + c
    if (i < 512 * 64) {
      int k = i >> 6, c = i & 63;
      Wt[(size_t)c * 512 + k] = f2bf(W[i]);
    }
    return;
  }
  __shared__ int h[512];
  for (int i = t; i < B; i += 256) h[i] = 0;
  __syncthreads();
  int e0 = blk * EPB;
#pragma unroll
  for (int i = 0; i < EPB / 256; ++i) {
    int e = e0 + i * 256 + t;
    if (e < E) atomicAdd(&h[dst[e] >> BKT_SHIFT], 1);
  }
  __syncthreads();
  for (int i = t; i < B; i += 256)
    if (h[i]) atomicAdd(bucketCount + i, h[i]);
}

__global__ __launch_bounds__(256) void k_bin(const int* __restrict__ src,
                                             const int* __restrict__ dst,
                                             const int* __restrict__ bucketCount,
                                             int* __restrict__ gCursorRel,
                                             unsigned* __restrict__ binned,
                                             int E, int B) {
  __shared__ int sc[512];
  __shared__ int hist[512];
  __shared__ int base[512];
  int t = threadIdx.x;
  sc[t]       = (t < B) ? bucketCount[t] : 0;
  sc[t + 256] = (t + 256 < B) ? bucketCount[t + 256] : 0;
  for (int i = t; i < 512; i += 256) hist[i] = 0;
  __syncthreads();
  for (int o = 1; o < 512; o <<= 1) {
    int a0 = (t >= o) ? sc[t - o] : 0;
    int a1 = (t + 256 >= o) ? sc[t + 256 - o] : 0;
    __syncthreads();
    sc[t] += a0;
    sc[t + 256] += a1;
    __syncthreads();
  }
  int e0 = blockIdx.x * EPB;
#pragma unroll
  for (int i = 0; i < EPB / 256; ++i) {
    int e = e0 + i * 256 + t;
    if (e < E) atomicAdd(&hist[dst[e] >> BKT_SHIFT], 1);
  }
  __syncthreads();
  for (int i = t; i < B; i += 256) {
    int c = hist[i];
    int excl = sc[i] - bucketCount[i];
    base[i] = c ? (excl + atomicAdd(gCursorRel + i, c)) : 0;
    hist[i] = 0;
  }
  __syncthreads();
#pragma unroll
  for (int i = 0; i < EPB / 256; ++i) {
    int e = e0 + i * 256 + t;
    if (e < E) {
      int d = dst[e];
      int b = d >> BKT_SHIFT;
      int r = atomicAdd(&hist[b], 1);
      binned[base[b] + r] = ((unsigned)(d & (BKT_RANGE - 1)) << 24) | (unsigned)src[e];
    }
  }
}

__global__ __launch_bounds__(256) void k_build(const int* __restrict__ bucketCount,
                                               const unsigned* __restrict__ binned,
                                               int* __restrict__ rowptr,
                                               int* __restrict__ deg,
                                               int* __restrict__ srt, int N, int B) {
  __shared__ int sc[512];
  __shared__ int ldeg[BKT_RANGE];
  __shared__ int sm[BKT_RANGE];
  __shared__ int lcur[BKT_RANGE];
  int t = threadIdx.x;
  int b = blockIdx.x;
  sc[t]       = (t < B) ? bucketCount[t] : 0;
  sc[t + 256] = (t + 256 < B) ? bucketCount[t + 256] : 0;
  ldeg[t] = 0;
  __syncthreads();
  for (int o = 1; o < 512; o <<= 1) {
    int a0 = (t >= o) ? sc[t - o] : 0;
    int a1 = (t + 256 >= o) ? sc[t + 256 - o] : 0;
    __syncthreads();
    sc[t] += a0;
    sc[t + 256] += a1;
    __syncthreads();
  }
  int eend = sc[b];
  int estart = eend - bucketCount[b];
  int nbase = b * BKT_RANGE;
  for (int e = estart + t; e < eend; e += 256)
    atomicAdd(&ldeg[binned[e] >> 24], 1);
  __syncthreads();
  int v = ldeg[t];
  sm[t] = v;
  __syncthreads();
  int acc = v;
#pragma unroll
  for (int o = 1; o < 256; o <<= 1) {
    int u = (t >= o) ? sm[t - o] : 0;
    __syncthreads();
    acc += u;
    sm[t] = acc;
    __syncthreads();
  }
  int excl = estart + acc - v;
  int node = nbase + t;
  if (node < N) {
    rowptr[node] = excl;
    deg[node] = v;
  }
  lcur[t] = excl;
  __syncthreads();
  for (int e = estart + t; e < eend; e += 256) {
    unsigned p = binned[e];
    int pos = atomicAdd(&lcur[p >> 24], 1);
    srt[pos] = (int)(p & 0xFFFFFFu);
  }
}

// ---------------- K agg1f: gather-reduce L1 (128B hx rows) + fused L2 node work ----------------
// wave per dst; slot = lane>>4 (4 edges in flight), c4 = lane&15 (4 channels);
// srt batch-loaded 64 at a time, distributed via shfl.
__global__ __launch_bounds__(256) void k_agg1f(const int* __restrict__ rowptr,
                                               const int* __restrict__ deg,
                                               const int* __restrict__ srt,
                                               const unsigned* __restrict__ hx,
                                               const float* __restrict__ b1,
                                               const float* __restrict__ W2,
                                               const float* __restrict__ a2s,
                                               const float* __restrict__ a2d,
                                               unsigned* __restrict__ h2x, int N) {
  __shared__ float vsm[4][64];
  const int t = threadIdx.x;
  const int w = t >> 6;
  const int lane = t & 63;
  const int wid = blockIdx.x * 4 + w;
  const int slot = lane >> 4;
  const int c4 = lane & 15;
  const int h = c4 >> 1;
  float a2sr = a2s[c4];
  float a2dr = a2d[c4];
  float wreg[16];
#pragma unroll
  for (int m = 0; m < 16; ++m) wreg[m] = W2[(slot * 16 + m) * 16 + c4];
  float4 b1v = *(const float4*)(b1 + c4 * 4);
  if (wid >= N) return;
  const int d = wid;

  unsigned ddu = hx[(size_t)d * 32 + 8 + h];
  float ddx = bflo(ddu), ddy = bfhi(ddu);
  // self loop (slot 0 only)
  unsigned es0 = hx[(size_t)d * 32 + h];
  unsigned sv = hx[(size_t)d * 32 + 16 + c4];
  float ex0 = fmaxf(bflo(es0) * ddx, bfhi(es0) * ddy);
  ex0 = (slot == 0) ? ex0 : 0.f;
  float a0 = ex0 * __builtin_amdgcn_cvt_f32_fp8(sv, 0);
  float a1 = ex0 * __builtin_amdgcn_cvt_f32_fp8(sv, 1);
  float a2 = ex0 * __builtin_amdgcn_cvt_f32_fp8(sv, 2);
  float a3 = ex0 * __builtin_amdgcn_cvt_f32_fp8(sv, 3);
  float den = ex0;

  int start = rowptr[d];
  int len = deg[d];
  for (int kb = 0; kb < len; kb += 64) {
    int li = kb + lane;
    int sreg = (li < len) ? srt[start + li] : 0;
    int nit = min(16, (len - kb + 3) >> 2);
#pragma unroll 4
    for (int it = 0; it < nit; ++it) {
      int idx = kb + it * 4 + slot;
      int s = __shfl(sreg, it * 4 + slot);
      bool valid = idx < len;
      unsigned es = hx[(size_t)s * 32 + h];
      unsigned hv = hx[(size_t)s * 32 + 16 + c4];
      float ex = fmaxf(bflo(es) * ddx, bfhi(es) * ddy);
      ex = valid ? ex : 0.f;
      a0 = fmaf(ex, __builtin_amdgcn_cvt_f32_fp8(hv, 0), a0);
      a1 = fmaf(ex, __builtin_amdgcn_cvt_f32_fp8(hv, 1), a1);
      a2 = fmaf(ex, __builtin_amdgcn_cvt_f32_fp8(hv, 2), a2);
      a3 = fmaf(ex, __builtin_amdgcn_cvt_f32_fp8(hv, 3), a3);
      den += ex;
    }
  }
#pragma unroll
  for (int o = 16; o < 64; o <<= 1) {
    a0 += __shfl_xor(a0, o);
    a1 += __shfl_xor(a1, o);
    a2 += __shfl_xor(a2, o);
    a3 += __shfl_xor(a3, o);
    den += __shfl_xor(den, o);
  }
  float rden = 1.f / (den + 1e-16f);
  if (slot == 0) {
    float4 vv;
    vv.x = elu1(a0 * rden + b1v.x);
    vv.y = elu1(a1 * rden + b1v.y);
    vv.z = elu1(a2 * rden + b1v.z);
    vv.w = elu1(a3 * rden + b1v.w);
    *(float4*)&vsm[w][c4 * 4] = vv;
  }
  float partial = 0.f;
#pragma unroll
  for (int m = 0; m < 16; ++m) partial = fmaf(vsm[w][slot * 16 + m], wreg[m], partial);
  float qs = partial * a2sr;
  float qd = partial * a2dr;
#pragma unroll
  for (int o = 1; o < 64; o <<= 1) {
    qs += __shfl_xor(qs, o);
    qd += __shfl_xor(qd, o);
  }
  float p2 = partial + __shfl_down(partial, 32);
  float hcv = p2 + __shfl_down(p2, 16);
  if (lane < 16)
    ((unsigned short*)h2x)[(size_t)d * 32 + 8 + c4] = f2bf(hcv);
  if (lane == 0) {
    h2x[(size_t)d * 16] = cvt_pk_bf16(expf(qs), expf(NEG_SLOPE * qs));
    *(float2*)(h2x + (size_t)d * 16 + 2) = make_float2(expf(qd), expf(NEG_SLOPE * qd));
  }
}

// ---------------- K agg2: gather-reduce layer 2 (64B h2x rows) + b2 + log_softmax ----------------
__global__ __launch_bounds__(256) void k_agg2(const int* __restrict__ rowptr,
                                              const int* __restrict__ deg,
                                              const int* __restrict__ srt,
                                              const unsigned* __restrict__ h2x,
                                              const float* __restrict__ b2,
                                              float* __restrict__ out, int N) {
  const int t = threadIdx.x;
  const int lane = t & 63;
  const int wid = (blockIdx.x * 256 + t) >> 6;
  const int slot = lane >> 2;
  const int cg = lane & 3;
  float4 b2v = *(const float4*)(b2 + cg * 4);
  if (wid >= N) return;
  const int d = wid;
  float2 ddp = *(const float2*)(h2x + (size_t)d * 16 + 2);
  unsigned ps0 = h2x[(size_t)d * 16];
  uint2 sv = *(const uint2*)(h2x + (size_t)d * 16 + 4 + cg * 2);
  float ex0 = fmaxf(bflo(ps0) * ddp.x, bfhi(ps0) * ddp.y);
  ex0 = (slot == 0) ? ex0 : 0.f;
  float a0 = ex0 * bflo(sv.x), a1 = ex0 * bfhi(sv.x);
  float a2 = ex0 * bflo(sv.y), a3 = ex0 * bfhi(sv.y);
  float den = ex0;

  int start = rowptr[d];
  int len = deg[d];
  for (int kb = 0; kb < len; kb += 64) {
    int li = kb + lane;
    int sreg = (li < len) ? srt[start + li] : 0;
    int nit = min(4, (len - kb + 15) >> 4);
#pragma unroll 4
    for (int it = 0; it < nit; ++it) {
      int idx = kb + it * 16 + slot;
      int s = __shfl(sreg, it * 16 + slot);
      bool valid = idx < len;
      unsigned ps = h2x[(size_t)s * 16];
      uint2 hv = *(const uint2*)(h2x + (size_t)s * 16 + 4 + cg * 2);
      float ex = fmaxf(bflo(ps) * ddp.x, bfhi(ps) * ddp.y);
      ex = valid ? ex : 0.f;
      a0 = fmaf(ex, bflo(hv.x), a0);
      a1 = fmaf(ex, bfhi(hv.x), a1);
      a2 = fmaf(ex, bflo(hv.y), a2);
      a3 = fmaf(ex, bfhi(hv.y), a3);
      den += ex;
    }
  }
#pragma unroll
  for (int o = 4; o < 64; o <<= 1) {
    a0 += __shfl_xor(a0, o);
    a1 += __shfl_xor(a1, o);
    a2 += __shfl_xor(a2, o);
    a3 += __shfl_xor(a3, o);
    den += __shfl_xor(den, o);
  }
  float rden = 1.f / (den + 1e-16f);
  float v0 = a0 * rden + b2v.x;
  float v1 = a1 * rden + b2v.y;
  float v2 = a2 * rden + b2v.z;
  float v3 = a3 * rden + b2v.w;
  float m = fmaxf(fmaxf(v0, v1), fmaxf(v2, v3));
  m = fmaxf(m, __shfl_xor(m, 1));
  m = fmaxf(m, __shfl_xor(m, 2));
  float s = expf(v0 - m) + expf(v1 - m) + expf(v2 - m) + expf(v3 - m);
  s += __shfl_xor(s, 1);
  s += __shfl_xor(s, 2);
  float lse = m + logf(s);
  if (lane < 4) {
    float4 o4 = make_float4(v0 - lse, v1 - lse, v2 - lse, v3 - lse);
    *(float4*)(out + (size_t)d * 16 + cg * 4) = o4;
  }
}

extern "C" void kernel_launch(void* const* d_in, const int* in_sizes, int n_in,
                              void* d_out, int out_size, void* d_ws, size_t ws_size,
                              hipStream_t stream) {
  const float* x    = (const float*)d_in[0];
  const int*   ei   = (const int*)d_in[1];
  const float* W1   = (const float*)d_in[2];
  const float* a1s  = (const float*)d_in[3];
  const float* a1d  = (const float*)d_in[4];
  const float* b1   = (const float*)d_in[5];
  const float* W2   = (const float*)d_in[6];
  const float* a2s  = (const float*)d_in[7];
  const float* a2d  = (const float*)d_in[8];
  const float* b2   = (const float*)d_in[9];
  float* out = (float*)d_out;

  const int N = in_sizes[0] / 512;
  const int E = in_sizes[1] / 2;
  const int* src = ei;
  const int* dst = ei + E;
  const int B = (N + BKT_RANGE - 1) >> BKT_SHIFT;
  const int EB = (E + EPB - 1) / EPB;

  float* w = (float*)d_ws;
  unsigned* hx  = (unsigned*)w;             w += (size_t)N * 32;   // 128B rows
  unsigned* h2x = (unsigned*)w;             w += (size_t)N * 16;   // 64B rows
  unsigned short* Wt = (unsigned short*)w;  w += 512 * 64 / 2;
  int* iw = (int*)w;
  int* deg         = iw;  iw += N;
  int* rowptr      = iw;  iw += N;
  int* bucketCount = iw;  iw += 512;
  int* gCursorRel  = iw;  iw += 512;
  int* srt         = iw;  iw += E;
  unsigned* binned = (unsigned*)iw;  iw += E;

  // zero bucketCount + gCursorRel (contiguous 1024 ints)
  (void)hipMemsetAsync(bucketCount, 0, 1024 * sizeof(int), stream);

  // CSR build (+ fused Wt conversion blocks)
  k_bhist_cvtW<<<EB + 128, 256, 0, stream>>>(dst, bucketCount, W1, Wt, E, B, EB);
  k_bin<<<EB, 256, 0, stream>>>(src, dst, bucketCount, gCursorRel, binned, E, B);
  k_build<<<B, 256, 0, stream>>>(bucketCount, binned, rowptr, deg, srt, N, B);

  // Layer 1: GEMM with fused alpha/fp8 epilogue, then gather (+fused L2 node work)
  k_gemm1_mfma<<<(N + 127) / 128, 256, 0, stream>>>(x, Wt, a1s, a1d, hx, N);
  k_agg1f<<<(N + 3) / 4, 256, 0, stream>>>(rowptr, deg, srt, hx,
                                           b1, W2, a2s, a2d, h2x, N);

  // Layer 2
  k_agg2<<<(N + 3) / 4, 256, 0, stream>>>(rowptr, deg, srt, h2x, b2, out, N);
}